// Round 8
// baseline (216.616 us; speedup 1.0000x reference)
//
#include <hip/hip_runtime.h>
#include <cstdint>

// ---------------------------------------------------------------------------
// COMPILE-TIME op list: constexpr replica of numpy's RNG stream.
// op = (kind<<4) | (w0<<2) | w1
// kinds: 0 RX, 1 RY, 2 RZ, 3 CRX(ctrl=w0,tgt=w1), 4 H, 5 SX, 6 CNOT(ctrl=w0,tgt=w1)
// ---------------------------------------------------------------------------
namespace crng {

typedef unsigned __int128 u128;

struct PCG {
    u128 state, inc;
    bool has32;
    uint32_t buf32;
};

constexpr u128 PCG_MULT = (((u128)2549297995355413924ULL) << 64) | (u128)4865540595714422341ULL;

constexpr uint64_t pcg_next64(PCG& g) {
    g.state = g.state * PCG_MULT + g.inc;
    uint64_t hi = (uint64_t)(g.state >> 64), lo = (uint64_t)g.state;
    unsigned rot = (unsigned)(g.state >> 122) & 63u;
    uint64_t v = hi ^ lo;
    return (v >> rot) | (v << ((64u - rot) & 63u));
}

constexpr uint32_t pcg_next32(PCG& g) {
    if (g.has32) { g.has32 = false; return g.buf32; }
    uint64_t n = pcg_next64(g);
    g.has32 = true;
    g.buf32 = (uint32_t)(n >> 32);
    return (uint32_t)n;
}

constexpr uint32_t hashmix(uint32_t& hc, uint32_t v) {
    v ^= hc; hc *= 0x931e8875u; v *= hc; v ^= v >> 16; return v;
}
constexpr uint32_t mixf(uint32_t x, uint32_t y) {
    uint32_t r = 0xca01f9ddu * x - 0x4973f715u * y;
    r ^= r >> 16;
    return r;
}

constexpr PCG seed_pcg(uint32_t entropy) {
    uint32_t pool[4] = {0, 0, 0, 0};
    uint32_t hc = 0x43b0d7e5u;
    pool[0] = hashmix(hc, entropy);
    for (int i = 1; i < 4; ++i) pool[i] = hashmix(hc, 0u);
    for (int s = 0; s < 4; ++s)
        for (int d = 0; d < 4; ++d)
            if (s != d) pool[d] = mixf(pool[d], hashmix(hc, pool[s]));

    uint32_t hb = 0x8b51f9ddu;
    uint32_t w[8] = {0, 0, 0, 0, 0, 0, 0, 0};
    for (int i = 0; i < 8; ++i) {
        uint32_t dv = pool[i & 3];
        dv ^= hb; hb *= 0x58f38dedu; dv *= hb; dv ^= dv >> 16;
        w[i] = dv;
    }
    uint64_t w64[4] = {0, 0, 0, 0};
    for (int i = 0; i < 4; ++i)
        w64[i] = (uint64_t)w[2 * i] | ((uint64_t)w[2 * i + 1] << 32);

    u128 initstate = (((u128)w64[0]) << 64) | (u128)w64[1];
    u128 initseq   = (((u128)w64[2]) << 64) | (u128)w64[3];
    PCG g = {};
    g.state = 0;
    g.inc = (initseq << 1) | (u128)1;
    g.state = g.state * PCG_MULT + g.inc;
    g.state += initstate;
    g.state = g.state * PCG_MULT + g.inc;
    g.has32 = false;
    g.buf32 = 0;
    return g;
}

constexpr uint32_t lemire32(PCG& g, uint32_t rng) {
    uint64_t rng_excl = (uint64_t)rng + 1;
    uint64_t m = (uint64_t)pcg_next32(g) * rng_excl;
    uint32_t leftover = (uint32_t)m;
    if (leftover < (uint32_t)rng_excl) {
        uint32_t threshold = (uint32_t)((uint64_t)(0xFFFFFFFFu - rng) % rng_excl);
        while (leftover < threshold) {
            m = (uint64_t)pcg_next32(g) * rng_excl;
            leftover = (uint32_t)m;
        }
    }
    return (uint32_t)(m >> 32);
}

struct Ops {
    int enc[8];
    int qfc[50];
};

constexpr void fill_ops(PCG& g, int n, int* out) {
    for (int i = 0; i < n; ++i) {
        uint32_t kind = lemire32(g, 3);
        uint32_t w0 = 0, w1 = 0;
        if (kind == 3) {
            uint32_t v2 = lemire32(g, 2);
            uint32_t v3 = lemire32(g, 3);
            uint32_t a0 = v2;
            uint32_t a1 = (v3 == v2) ? 3u : v3;
            uint32_t j = lemire32(g, 1);
            if (j == 0) { uint32_t t = a0; a0 = a1; a1 = t; }
            w0 = a0; w1 = a1;
        } else {
            w0 = lemire32(g, 3);
        }
        out[i] = (int)((kind << 4) | (w0 << 2) | w1);
    }
}

constexpr Ops make_ops_ct() {
    Ops o = {};
    PCG g1 = seed_pcg(1u);
    fill_ops(g1, 8, o.enc);
    PCG g2 = seed_pcg(2u);
    fill_ops(g2, 50, o.qfc);
    return o;
}

}  // namespace crng

constexpr crng::Ops kOps = crng::make_ops_ct();

// ---------------------------------------------------------------------------
typedef _Float16 half8 __attribute__((ext_vector_type(8)));
typedef _Float16 half2v __attribute__((ext_vector_type(2)));
typedef float float4v __attribute__((ext_vector_type(4)));

#define XS_STRIDE 24
#define XS_PLANE  (34 * XS_STRIDE)
#define XS_TOT    (2 * XS_PLANE)     // 1632 floats (div by 4)
#define H1F_ROW   (18 * 8)           // halves per row
#define H1F_TOT   (18 * H1F_ROW)     // 2592 halves (div by 8)

// ---------------------------------------------------------------------------
// Kernel 1: conv1 (packed f16 VALU) + pool -> h1f(f16) -> conv2 via MFMA
//           implicit GEMM -> pool/relu/mean via shuffles -> pm.
// One block per image.
// ---------------------------------------------------------------------------
__global__ __launch_bounds__(256, 4) void cnn_kernel(
    const float* __restrict__ x, const float* __restrict__ w1,
    const float* __restrict__ b1, const float* __restrict__ w2,
    const float* __restrict__ b2, float* __restrict__ pm,
    float* __restrict__ stats)
{
    __shared__ __align__(16) float xs[XS_TOT];
    __shared__ __align__(16) _Float16 h1f[H1F_TOT];
    __shared__ __align__(16) _Float16 Ahalf[9 * 16 * 8];
    __shared__ _Float16 w1h[72], b1h[8];
    __shared__ float b2s[16];

    const int tid = threadIdx.x;
    const int b = blockIdx.x;
    const float* xb = x + (size_t)b * 1024;

    // vector zero of halo regions
    for (int k = tid; k < XS_TOT / 4; k += 256)
        ((float4*)xs)[k] = make_float4(0.f, 0.f, 0.f, 0.f);
    for (int k = tid; k < H1F_TOT / 8; k += 256)
        ((half8*)h1f)[k] = (half8)0;
    for (int e = tid; e < 1152; e += 256) {
        int uv = e >> 7, m = (e >> 3) & 15, ci = e & 7;
        Ahalf[e] = (_Float16)w2[m * 72 + ci * 9 + uv];
    }
    if (tid < 72) w1h[tid] = (_Float16)w1[tid];
    if (tid < 8) b1h[tid] = (_Float16)b1[tid];
    if (tid < 16) b2s[tid] = b2[tid];
    if (b == 0 && tid < 8) stats[tid] = 0.f;
    __syncthreads();

    // fill xs interior (even/odd column split, conflict-free)
    for (int k = tid; k < 1024; k += 256) {
        int r = k >> 5, c = k & 31;
        int p = c & 1;
        int q = p ? ((c + 1) >> 1) : (c >> 1);
        xs[p * XS_PLANE + (r + 1) * XS_STRIDE + q] = xb[k];
    }
    __syncthreads();

    // ---- conv1 + relu + pool (packed f16), write f16 [row][col][ci] ----
    {
        const int i = tid >> 4, j = tid & 15;
        _Float16 ph[4][4];
#pragma unroll
        for (int u = 0; u < 4; ++u) {
            int r = 2 * i + u;
            const float* ev = &xs[r * XS_STRIDE + j];
            const float* od = &xs[XS_PLANE + r * XS_STRIDE + j];
            ph[u][0] = (_Float16)od[0];
            ph[u][1] = (_Float16)ev[0];
            ph[u][2] = (_Float16)od[1];
            ph[u][3] = (_Float16)ev[1];
        }
        half8 hv;
#pragma unroll
        for (int c = 0; c < 8; ++c) {
            half2v acc0 = {b1h[c], b1h[c]};   // dj = 0,1 packed; di = 0
            half2v acc1 = acc0;               // di = 1
#pragma unroll
            for (int u = 0; u < 3; ++u) {
#pragma unroll
                for (int v = 0; v < 3; ++v) {
                    _Float16 w = w1h[c * 9 + u * 3 + v];
                    half2v wv = {w, w};
                    half2v p0 = {ph[u][v], ph[u][v + 1]};
                    half2v p1 = {ph[u + 1][v], ph[u + 1][v + 1]};
                    acc0 += wv * p0;
                    acc1 += wv * p1;
                }
            }
            _Float16 m0 = (acc0.x > acc0.y) ? acc0.x : acc0.y;
            _Float16 m1 = (acc1.x > acc1.y) ? acc1.x : acc1.y;
            _Float16 mm = (m0 > m1) ? m0 : m1;
            hv[c] = (mm > (_Float16)0.f) ? mm : (_Float16)0.f;
        }
        *(half8*)&h1f[(i + 1) * H1F_ROW + (j + 1) * 8] = hv;
    }
    __syncthreads();

    // ---- conv2 as MFMA implicit GEMM (verified R7 layout) ----
    {
        const int w = tid >> 6;
        const int lane = tid & 63;
        const int pj = lane & 15;
        const int quad = lane >> 4;

        half8 afrag[9];
#pragma unroll
        for (int uv = 0; uv < 9; ++uv) {
            half8 a = {};
            if (quad == 0) a = *(const half8*)&Ahalf[(uv * 16 + pj) * 8];
            afrag[uv] = a;
        }

        float4v acc[4];
#pragma unroll
        for (int tl = 0; tl < 4; ++tl) {
            float4v c;
#pragma unroll
            for (int r = 0; r < 4; ++r) c[r] = b2s[4 * quad + r];
            acc[tl] = c;
        }

#pragma unroll
        for (int tl = 0; tl < 4; ++tl) {
            const int t = 4 * w + tl;
#pragma unroll
            for (int u = 0; u < 3; ++u) {
#pragma unroll
                for (int v = 0; v < 3; ++v) {
                    half8 bf = *(const half8*)&h1f[(t + u) * H1F_ROW + (pj + v) * 8];
                    acc[tl] = __builtin_amdgcn_mfma_f32_16x16x32_f16(
                        afrag[u * 3 + v], bf, acc[tl], 0, 0, 0);
                }
            }
        }

#pragma unroll
        for (int p = 0; p < 2; ++p) {
            float4v m1;
#pragma unroll
            for (int r = 0; r < 4; ++r)
                m1[r] = fmaxf(acc[2 * p][r], acc[2 * p + 1][r]);
            float s = 0.f;
#pragma unroll
            for (int r = 0; r < 4; ++r) {
                float o = __shfl_xor((float)m1[r], 1, 64);
                float mv = fmaxf(fmaxf(m1[r], o), 0.f);
                s += mv;
            }
            s += __shfl_xor(s, 16, 64);
            s += __shfl_xor(s, 32, 64);
            if (quad == 0 && !(pj & 1)) {
                const int i2 = 2 * w + p, j2 = pj >> 1;
                pm[(size_t)b * 64 + i2 * 8 + j2] = s * (1.f / 16.f);
            }
        }
    }
}

// ---------------------------------------------------------------------------
// Compile-time gate on a register-resident 16-dim complex state.
// ---------------------------------------------------------------------------
template<int KIND, int W0, int W1>
__device__ __forceinline__ void gate_ct(float (&ur)[16], float (&ui)[16],
                                        float ch, float sh)
{
    constexpr bool CTRL = (KIND == 3 || KIND == 6);
    constexpr int STT = CTRL ? (8 >> W1) : (8 >> W0);
    constexpr int STC = CTRL ? (8 >> W0) : 0;
#pragma unroll
    for (int k0 = 0; k0 < 16; ++k0) {
        if (k0 & STT) continue;
        if (STC != 0 && !(k0 & STC)) continue;
        const int k1 = k0 | STT;
        float x0r = ur[k0], x0i = ui[k0], x1r = ur[k1], x1i = ui[k1];
        if constexpr (KIND == 0 || KIND == 3) {        // RX / CRX
            ur[k0] = ch * x0r + sh * x1i;  ui[k0] = ch * x0i - sh * x1r;
            ur[k1] = sh * x0i + ch * x1r;  ui[k1] = -sh * x0r + ch * x1i;
        } else if constexpr (KIND == 1) {              // RY
            ur[k0] = ch * x0r - sh * x1r;  ui[k0] = ch * x0i - sh * x1i;
            ur[k1] = sh * x0r + ch * x1r;  ui[k1] = sh * x0i + ch * x1i;
        } else if constexpr (KIND == 2) {              // RZ
            ur[k0] = ch * x0r + sh * x0i;  ui[k0] = ch * x0i - sh * x0r;
            ur[k1] = ch * x1r - sh * x1i;  ui[k1] = ch * x1i + sh * x1r;
        } else if constexpr (KIND == 4) {              // H
            constexpr float RH = 0.70710678118654752f;
            ur[k0] = RH * (x0r + x1r);  ui[k0] = RH * (x0i + x1i);
            ur[k1] = RH * (x0r - x1r);  ui[k1] = RH * (x0i - x1i);
        } else if constexpr (KIND == 5) {              // SX
            ur[k0] = 0.5f * (x0r + x1r) - 0.5f * x0i + 0.5f * x1i;
            ui[k0] = 0.5f * (x0i + x1i) + 0.5f * x0r - 0.5f * x1r;
            ur[k1] = 0.5f * (x0r + x1r) + 0.5f * x0i - 0.5f * x1i;
            ui[k1] = 0.5f * (x0i + x1i) - 0.5f * x0r + 0.5f * x1r;
        } else {                                       // CNOT
            ur[k0] = x1r; ui[k0] = x1i;
            ur[k1] = x0r; ui[k1] = x0i;
        }
    }
}

template<int I>
__device__ __forceinline__ void run_enc(float (&ur)[16], float (&ui)[16],
                                        const float* ch, const float* sh)
{
    if constexpr (I < 8) {
        constexpr int op = kOps.enc[I];
        gate_ct<(op >> 4) & 7, (op >> 2) & 3, op & 3>(ur, ui, ch[I], sh[I]);
        run_enc<I + 1>(ur, ui, ch, sh);
    }
}

template<int I>
__device__ __forceinline__ void run_qfc(float (&ur)[16], float (&ui)[16],
                                        const float* ch, const float* sh)
{
    if constexpr (I < 50) {
        constexpr int op = kOps.qfc[I];
        gate_ct<(op >> 4) & 7, (op >> 2) & 3, op & 3>(ur, ui, ch[I], sh[I]);
        run_qfc<I + 1>(ur, ui, ch, sh);
    }
}

// ---------------------------------------------------------------------------
// Kernel 2: register-resident quantum sim. Thread = one patch.
// qfeat now written TRANSPOSED: qfeatT[f][b], f = 4p + w  (coalesced head reads)
// ---------------------------------------------------------------------------
__global__ __launch_bounds__(256) void quantum_kernel(
    const float* __restrict__ pm, const float* __restrict__ encp,
    const float* __restrict__ qfcr, const float* __restrict__ qfcp,
    float* __restrict__ qfeatT, float* __restrict__ qraw,
    float* __restrict__ stats, int Bv)
{
    __shared__ float chs[62], shs[62];
    __shared__ float rstat[128];

    const int tid = threadIdx.x;
    if (tid < 62) {
        float t = (tid < 8) ? encp[tid] : (tid < 58) ? qfcr[tid - 8] : qfcp[tid - 58];
        chs[tid] = cosf(0.5f * t);
        shs[tid] = sinf(0.5f * t);
    }
    __syncthreads();

    const int gid = blockIdx.x * 256 + tid;
    const int b = gid >> 4, p = gid & 15;
    float qq[4] = {0.f, 0.f, 0.f, 0.f};
    bool last = false;

    if (b < Bv) {
        const int pr = p >> 2, pc = p & 3;
        const float* pmb = pm + (size_t)b * 64;
        float d0 = pmb[(2 * pr) * 8 + 2 * pc];
        float d1 = pmb[(2 * pr) * 8 + 2 * pc + 1];
        float d2 = pmb[(2 * pr + 1) * 8 + 2 * pc];
        float d3 = pmb[(2 * pr + 1) * 8 + 2 * pc + 1];
        float f0c = cosf(0.5f * d0), f0s = sinf(0.5f * d0);
        float f1c = cosf(0.5f * d1), f1s = sinf(0.5f * d1);
        float f2c = cosf(0.5f * d2), f2s = sinf(0.5f * d2);
        float f3c = cosf(0.5f * d3), f3s = sinf(0.5f * d3);

        float ur[16], ui[16];
#pragma unroll
        for (int k = 0; k < 16; ++k) {
            float v = ((k & 8) ? f0s : f0c);
            v *= ((k & 4) ? f1s : f1c);
            v *= ((k & 2) ? f2s : f2c);
            v *= ((k & 1) ? f3s : f3c);
            ur[k] = v;
            ui[k] = 0.f;
        }
        run_enc<0>(ur, ui, chs, shs);

        float qv[4] = {0.f, 0.f, 0.f, 0.f};
#pragma unroll
        for (int k = 0; k < 16; ++k) {
            float pk = ur[k] * ur[k] + ui[k] * ui[k];
            qv[0] += (k & 8) ? -pk : pk;
            qv[1] += (k & 4) ? -pk : pk;
            qv[2] += (k & 2) ? -pk : pk;
            qv[3] += (k & 1) ? -pk : pk;
        }
#pragma unroll
        for (int w = 0; w < 4; ++w)
            qfeatT[(size_t)(p * 4 + w) * Bv + b] = qv[w];

        if (p == 15) {
            last = true;
            run_qfc<0>(ur, ui, chs + 8, shs + 8);
            gate_ct<0, 0, 0>(ur, ui, chs[58], shs[58]);  // RX wire0
            gate_ct<1, 1, 0>(ur, ui, chs[59], shs[59]);  // RY wire1
            gate_ct<2, 3, 0>(ur, ui, chs[60], shs[60]);  // RZ wire3
            gate_ct<3, 0, 2>(ur, ui, chs[61], shs[61]);  // CRX ctrl0 tgt2
            gate_ct<4, 3, 0>(ur, ui, 0.f, 0.f);          // H wire3
            gate_ct<5, 2, 0>(ur, ui, 0.f, 0.f);          // SX wire2
            gate_ct<6, 3, 0>(ur, ui, 0.f, 0.f);          // CNOT ctrl3 tgt0
#pragma unroll
            for (int k = 0; k < 16; ++k) {
                float pk = ur[k] * ur[k] + ui[k] * ui[k];
                qq[0] += (k & 8) ? -pk : pk;
                qq[1] += (k & 4) ? -pk : pk;
                qq[2] += (k & 2) ? -pk : pk;
                qq[3] += (k & 1) ? -pk : pk;
            }
            *(float4*)(qraw + (size_t)b * 4) = make_float4(qq[0], qq[1], qq[2], qq[3]);
        }
    }

    for (int k = tid; k < 128; k += 256) rstat[k] = 0.f;
    __syncthreads();
    const int m = tid >> 4;
    if (last) {
#pragma unroll
        for (int w = 0; w < 4; ++w) {
            rstat[w * 16 + m] = qq[w];
            rstat[64 + w * 16 + m] = qq[w] * qq[w];
        }
    }
    __syncthreads();
    if (tid < 8) {
        float s = 0.f;
#pragma unroll
        for (int k = 0; k < 16; ++k) s += rstat[tid * 16 + k];
        atomicAdd(&stats[tid], s);
    }
}

// ---------------------------------------------------------------------------
// Kernel 3: BN apply + FC(68->10) + log_softmax. 64 thr/block, 64 blocks.
// qfeatT layout -> fully coalesced feature reads.
// ---------------------------------------------------------------------------
__global__ __launch_bounds__(64) void head_kernel(
    const float* __restrict__ qfeatT, const float* __restrict__ qraw,
    const float* __restrict__ stats, const float* __restrict__ gam,
    const float* __restrict__ bet, const float* __restrict__ fcw,
    const float* __restrict__ fcb, float* __restrict__ out, int Bv)
{
    __shared__ float Wf[680];
    __shared__ float bf[10], st[8], ga[4], be[4];
    const int tid = threadIdx.x;
    for (int k = tid; k < 680; k += 64) Wf[k] = fcw[k];
    if (tid < 10) bf[tid] = fcb[tid];
    if (tid < 8) st[tid] = stats[tid];
    if (tid < 4) { ga[tid] = gam[tid]; be[tid] = bet[tid]; }
    __syncthreads();

    const int b = blockIdx.x * 64 + tid;
    if (b >= Bv) return;

    const float invB = 1.f / (float)Bv;

    float logit[10];
#pragma unroll
    for (int k = 0; k < 10; ++k) logit[k] = bf[k];

    for (int f = 0; f < 64; ++f) {
        float v = qfeatT[(size_t)f * Bv + b];
#pragma unroll
        for (int k = 0; k < 10; ++k) logit[k] += v * Wf[k * 68 + f];
    }
    float4 qr = *(const float4*)(qraw + (size_t)b * 4);
    float qn[4] = {qr.x, qr.y, qr.z, qr.w};
#pragma unroll
    for (int w = 0; w < 4; ++w) {
        float mu = st[w] * invB;
        float var = st[4 + w] * invB - mu * mu;
        float v = (qn[w] - mu) / sqrtf(var + 1e-5f) * ga[w] + be[w];
#pragma unroll
        for (int k = 0; k < 10; ++k) logit[k] += v * Wf[k * 68 + 64 + w];
    }

    float m = logit[0];
#pragma unroll
    for (int k = 1; k < 10; ++k) m = fmaxf(m, logit[k]);
    float sum = 0.f;
#pragma unroll
    for (int k = 0; k < 10; ++k) sum += expf(logit[k] - m);
    float lse = logf(sum);
#pragma unroll
    for (int k = 0; k < 10; ++k) out[(size_t)b * 10 + k] = logit[k] - m - lse;
}

// ---------------------------------------------------------------------------
extern "C" void kernel_launch(void* const* d_in, const int* in_sizes, int n_in,
                              void* d_out, int out_size, void* d_ws, size_t ws_size,
                              hipStream_t stream)
{
    const float* x    = (const float*)d_in[0];
    const float* w1   = (const float*)d_in[1];
    const float* b1   = (const float*)d_in[2];
    const float* w2   = (const float*)d_in[3];
    const float* b2   = (const float*)d_in[4];
    const float* encp = (const float*)d_in[5];
    const float* qfcr = (const float*)d_in[6];
    const float* qfcp = (const float*)d_in[7];
    const float* gam  = (const float*)d_in[8];
    const float* bet  = (const float*)d_in[9];
    const float* fcw  = (const float*)d_in[10];
    const float* fcb  = (const float*)d_in[11];
    float* out = (float*)d_out;

    const int Bv = in_sizes[0] / 1024;  // 4096

    float* pm     = (float*)d_ws;                // Bv*64
    float* qfeatT = pm + (size_t)Bv * 64;        // 64*Bv (transposed)
    float* qraw   = qfeatT + (size_t)Bv * 64;    // Bv*4
    float* stats  = qraw + (size_t)Bv * 4;       // 8

    cnn_kernel<<<Bv, 256, 0, stream>>>(x, w1, b1, w2, b2, pm, stats);
    quantum_kernel<<<(Bv * 16 + 255) / 256, 256, 0, stream>>>(
        pm, encp, qfcr, qfcp, qfeatT, qraw, stats, Bv);
    head_kernel<<<(Bv + 63) / 64, 64, 0, stream>>>(qfeatT, qraw, stats, gam, bet,
                                                   fcw, fcb, out, Bv);
}

// Round 9
// 139.283 us; speedup vs baseline: 1.5552x; 1.5552x over previous
//
#include <hip/hip_runtime.h>
#include <cstdint>

// ---------------------------------------------------------------------------
// COMPILE-TIME op list: constexpr replica of numpy's RNG stream.
// op = (kind<<4) | (w0<<2) | w1
// kinds: 0 RX, 1 RY, 2 RZ, 3 CRX(ctrl=w0,tgt=w1), 4 H, 5 SX, 6 CNOT(ctrl=w0,tgt=w1)
// ---------------------------------------------------------------------------
namespace crng {

typedef unsigned __int128 u128;

struct PCG {
    u128 state, inc;
    bool has32;
    uint32_t buf32;
};

constexpr u128 PCG_MULT = (((u128)2549297995355413924ULL) << 64) | (u128)4865540595714422341ULL;

constexpr uint64_t pcg_next64(PCG& g) {
    g.state = g.state * PCG_MULT + g.inc;
    uint64_t hi = (uint64_t)(g.state >> 64), lo = (uint64_t)g.state;
    unsigned rot = (unsigned)(g.state >> 122) & 63u;
    uint64_t v = hi ^ lo;
    return (v >> rot) | (v << ((64u - rot) & 63u));
}

constexpr uint32_t pcg_next32(PCG& g) {
    if (g.has32) { g.has32 = false; return g.buf32; }
    uint64_t n = pcg_next64(g);
    g.has32 = true;
    g.buf32 = (uint32_t)(n >> 32);
    return (uint32_t)n;
}

constexpr uint32_t hashmix(uint32_t& hc, uint32_t v) {
    v ^= hc; hc *= 0x931e8875u; v *= hc; v ^= v >> 16; return v;
}
constexpr uint32_t mixf(uint32_t x, uint32_t y) {
    uint32_t r = 0xca01f9ddu * x - 0x4973f715u * y;
    r ^= r >> 16;
    return r;
}

constexpr PCG seed_pcg(uint32_t entropy) {
    uint32_t pool[4] = {0, 0, 0, 0};
    uint32_t hc = 0x43b0d7e5u;
    pool[0] = hashmix(hc, entropy);
    for (int i = 1; i < 4; ++i) pool[i] = hashmix(hc, 0u);
    for (int s = 0; s < 4; ++s)
        for (int d = 0; d < 4; ++d)
            if (s != d) pool[d] = mixf(pool[d], hashmix(hc, pool[s]));

    uint32_t hb = 0x8b51f9ddu;
    uint32_t w[8] = {0, 0, 0, 0, 0, 0, 0, 0};
    for (int i = 0; i < 8; ++i) {
        uint32_t dv = pool[i & 3];
        dv ^= hb; hb *= 0x58f38dedu; dv *= hb; dv ^= dv >> 16;
        w[i] = dv;
    }
    uint64_t w64[4] = {0, 0, 0, 0};
    for (int i = 0; i < 4; ++i)
        w64[i] = (uint64_t)w[2 * i] | ((uint64_t)w[2 * i + 1] << 32);

    u128 initstate = (((u128)w64[0]) << 64) | (u128)w64[1];
    u128 initseq   = (((u128)w64[2]) << 64) | (u128)w64[3];
    PCG g = {};
    g.state = 0;
    g.inc = (initseq << 1) | (u128)1;
    g.state = g.state * PCG_MULT + g.inc;
    g.state += initstate;
    g.state = g.state * PCG_MULT + g.inc;
    g.has32 = false;
    g.buf32 = 0;
    return g;
}

constexpr uint32_t lemire32(PCG& g, uint32_t rng) {
    uint64_t rng_excl = (uint64_t)rng + 1;
    uint64_t m = (uint64_t)pcg_next32(g) * rng_excl;
    uint32_t leftover = (uint32_t)m;
    if (leftover < (uint32_t)rng_excl) {
        uint32_t threshold = (uint32_t)((uint64_t)(0xFFFFFFFFu - rng) % rng_excl);
        while (leftover < threshold) {
            m = (uint64_t)pcg_next32(g) * rng_excl;
            leftover = (uint32_t)m;
        }
    }
    return (uint32_t)(m >> 32);
}

struct Ops {
    int enc[8];
    int qfc[50];
};

constexpr void fill_ops(PCG& g, int n, int* out) {
    for (int i = 0; i < n; ++i) {
        uint32_t kind = lemire32(g, 3);
        uint32_t w0 = 0, w1 = 0;
        if (kind == 3) {
            uint32_t v2 = lemire32(g, 2);
            uint32_t v3 = lemire32(g, 3);
            uint32_t a0 = v2;
            uint32_t a1 = (v3 == v2) ? 3u : v3;
            uint32_t j = lemire32(g, 1);
            if (j == 0) { uint32_t t = a0; a0 = a1; a1 = t; }
            w0 = a0; w1 = a1;
        } else {
            w0 = lemire32(g, 3);
        }
        out[i] = (int)((kind << 4) | (w0 << 2) | w1);
    }
}

constexpr Ops make_ops_ct() {
    Ops o = {};
    PCG g1 = seed_pcg(1u);
    fill_ops(g1, 8, o.enc);
    PCG g2 = seed_pcg(2u);
    fill_ops(g2, 50, o.qfc);
    return o;
}

}  // namespace crng

constexpr crng::Ops kOps = crng::make_ops_ct();

// ---------------------------------------------------------------------------
// MFMA fragment types
// ---------------------------------------------------------------------------
typedef _Float16 half8 __attribute__((ext_vector_type(8)));
typedef float float4v __attribute__((ext_vector_type(4)));

// ---------------------------------------------------------------------------
// cnn LDS layout: xs even/odd split (conflict-free conv1);
// h1f: pooled conv1 as f16, [row 0..17][col 0..17][ci 0..7] (halo=0),
//      ci-contiguous -> conv2 B-fragment = one ds_read_b128 broadcast.
// Ahalf: conv2 weights f16 [uv 0..8][och 0..15][ci 0..7].
// ---------------------------------------------------------------------------
#define XS_STRIDE 24
#define XS_PLANE  (34 * XS_STRIDE)
#define XS_TOT    (2 * XS_PLANE)
#define H1F_ROW   (18 * 8)   // halves per row

// ---------------------------------------------------------------------------
// Kernel 1: conv1(fp32 VALU)+pool -> h1f(f16) -> conv2 via MFMA implicit GEMM
//           -> pool/relu/mean via shuffles -> pm. One block per image.
// NOTE: conv1 stays fp32 — an f16-packed variant (R8) collapsed VALUBusy
// 90%->13% (ds_read_u16 + pack/cvt latency chains) and tripled duration.
// ---------------------------------------------------------------------------
__global__ __launch_bounds__(256, 4) void cnn_kernel(
    const float* __restrict__ x, const float* __restrict__ w1,
    const float* __restrict__ b1, const float* __restrict__ w2,
    const float* __restrict__ b2, float* __restrict__ pm,
    float* __restrict__ stats)
{
    __shared__ float xs[XS_TOT];
    __shared__ __align__(16) _Float16 h1f[18 * H1F_ROW];   // 2592 halves
    __shared__ __align__(16) _Float16 Ahalf[9 * 16 * 8];   // 1152 halves
    __shared__ float w1s[72], b1s[8], b2s[16];

    const int tid = threadIdx.x;
    const int b = blockIdx.x;
    const float* xb = x + (size_t)b * 1024;

    // zero xs (halo) and h1f (halo); build Ahalf from global w2 (f16)
    for (int k = tid; k < XS_TOT; k += 256) xs[k] = 0.f;
    for (int k = tid; k < 18 * H1F_ROW; k += 256) h1f[k] = (_Float16)0.f;
    for (int e = tid; e < 1152; e += 256) {
        int uv = e >> 7, m = (e >> 3) & 15, ci = e & 7;
        Ahalf[e] = (_Float16)w2[m * 72 + ci * 9 + uv];
    }
    if (tid < 72) w1s[tid] = w1[tid];
    if (tid < 8) b1s[tid] = b1[tid];
    if (tid < 16) b2s[tid] = b2[tid];
    if (b == 0 && tid < 8) stats[tid] = 0.f;
    __syncthreads();

    // fill xs interior (even/odd column split)
    for (int k = tid; k < 1024; k += 256) {
        int r = k >> 5, c = k & 31;
        int p = c & 1;
        int q = p ? ((c + 1) >> 1) : (c >> 1);
        xs[p * XS_PLANE + (r + 1) * XS_STRIDE + q] = xb[k];
    }
    __syncthreads();

    // ---- conv1 + relu + pool (fp32), write f16 [row][col][ci] packed ----
    {
        const int i = tid >> 4, j = tid & 15;
        float patch[4][4];
#pragma unroll
        for (int u = 0; u < 4; ++u) {
            int r = 2 * i + u;
            const float* ev = &xs[r * XS_STRIDE + j];
            const float* od = &xs[XS_PLANE + r * XS_STRIDE + j];
            patch[u][0] = od[0];
            patch[u][1] = ev[0];
            patch[u][2] = od[1];
            patch[u][3] = ev[1];
        }
        half8 hv;
#pragma unroll
        for (int c = 0; c < 8; ++c) {
            float m = -3.4e38f;
#pragma unroll
            for (int di = 0; di < 2; ++di)
#pragma unroll
                for (int dj = 0; dj < 2; ++dj) {
                    float acc = b1s[c];
#pragma unroll
                    for (int u = 0; u < 3; ++u)
#pragma unroll
                        for (int v = 0; v < 3; ++v)
                            acc += w1s[c * 9 + u * 3 + v] * patch[di + u][dj + v];
                    m = fmaxf(m, acc);
                }
            hv[c] = (_Float16)fmaxf(m, 0.f);
        }
        *(half8*)&h1f[(i + 1) * H1F_ROW + (j + 1) * 8] = hv;
    }
    __syncthreads();

    // ---- conv2 as MFMA implicit GEMM ----
    // D[och][pos] = sum_{u,v} A_uv[och][ci] * h1f[ci][pi+u-1][pj+v-1]
    // wave w handles tiles (conv rows) 4w..4w+3; lane: pj = lane&15, quad = lane>>4
    {
        const int w = tid >> 6;
        const int lane = tid & 63;
        const int pj = lane & 15;
        const int quad = lane >> 4;

        // preload 9 A fragments: quad0 holds real weights (k=ci<8), quads 1-3 zero
        half8 afrag[9];
#pragma unroll
        for (int uv = 0; uv < 9; ++uv) {
            half8 a = {};
            if (quad == 0) a = *(const half8*)&Ahalf[(uv * 16 + pj) * 8];
            afrag[uv] = a;
        }

        float4v acc[4];
#pragma unroll
        for (int tl = 0; tl < 4; ++tl) {
            float4v c;
#pragma unroll
            for (int r = 0; r < 4; ++r) c[r] = b2s[4 * quad + r];
            acc[tl] = c;
        }

#pragma unroll
        for (int tl = 0; tl < 4; ++tl) {
            const int t = 4 * w + tl;  // conv output row pi
#pragma unroll
            for (int u = 0; u < 3; ++u) {
#pragma unroll
                for (int v = 0; v < 3; ++v) {
                    // B: all quads read same address -> LDS broadcast
                    half8 bf = *(const half8*)&h1f[(t + u) * H1F_ROW + (pj + v) * 8];
                    acc[tl] = __builtin_amdgcn_mfma_f32_16x16x32_f16(
                        afrag[u * 3 + v], bf, acc[tl], 0, 0, 0);
                }
            }
        }

        // ---- pool(2x2) + relu + channel-mean, registers/shuffles ----
        // acc[tl][r] = D[och=4*quad+r][pi=4w+tl][pj]
#pragma unroll
        for (int p = 0; p < 2; ++p) {
            float4v m1;
#pragma unroll
            for (int r = 0; r < 4; ++r)
                m1[r] = fmaxf(acc[2 * p][r], acc[2 * p + 1][r]);
            float s = 0.f;
#pragma unroll
            for (int r = 0; r < 4; ++r) {
                float o = __shfl_xor((float)m1[r], 1, 64);
                float mv = fmaxf(fmaxf(m1[r], o), 0.f);  // pool + relu
                s += mv;
            }
            s += __shfl_xor(s, 16, 64);
            s += __shfl_xor(s, 32, 64);
            if (quad == 0 && !(pj & 1)) {
                const int i2 = 2 * w + p, j2 = pj >> 1;
                pm[(size_t)b * 64 + i2 * 8 + j2] = s * (1.f / 16.f);
            }
        }
    }
}

// ---------------------------------------------------------------------------
// Compile-time gate on a register-resident 16-dim complex state.
// Wire w <-> bit (3-w). All masks template constants -> straight-line FMA.
// ---------------------------------------------------------------------------
template<int KIND, int W0, int W1>
__device__ __forceinline__ void gate_ct(float (&ur)[16], float (&ui)[16],
                                        float ch, float sh)
{
    constexpr bool CTRL = (KIND == 3 || KIND == 6);
    constexpr int STT = CTRL ? (8 >> W1) : (8 >> W0);
    constexpr int STC = CTRL ? (8 >> W0) : 0;
#pragma unroll
    for (int k0 = 0; k0 < 16; ++k0) {
        if (k0 & STT) continue;
        if (STC != 0 && !(k0 & STC)) continue;
        const int k1 = k0 | STT;
        float x0r = ur[k0], x0i = ui[k0], x1r = ur[k1], x1i = ui[k1];
        if constexpr (KIND == 0 || KIND == 3) {        // RX / CRX
            ur[k0] = ch * x0r + sh * x1i;  ui[k0] = ch * x0i - sh * x1r;
            ur[k1] = sh * x0i + ch * x1r;  ui[k1] = -sh * x0r + ch * x1i;
        } else if constexpr (KIND == 1) {              // RY
            ur[k0] = ch * x0r - sh * x1r;  ui[k0] = ch * x0i - sh * x1i;
            ur[k1] = sh * x0r + ch * x1r;  ui[k1] = sh * x0i + ch * x1i;
        } else if constexpr (KIND == 2) {              // RZ
            ur[k0] = ch * x0r + sh * x0i;  ui[k0] = ch * x0i - sh * x0r;
            ur[k1] = ch * x1r - sh * x1i;  ui[k1] = ch * x1i + sh * x1r;
        } else if constexpr (KIND == 4) {              // H
            constexpr float RH = 0.70710678118654752f;
            ur[k0] = RH * (x0r + x1r);  ui[k0] = RH * (x0i + x1i);
            ur[k1] = RH * (x0r - x1r);  ui[k1] = RH * (x0i - x1i);
        } else if constexpr (KIND == 5) {              // SX
            ur[k0] = 0.5f * (x0r + x1r) - 0.5f * x0i + 0.5f * x1i;
            ui[k0] = 0.5f * (x0i + x1i) + 0.5f * x0r - 0.5f * x1r;
            ur[k1] = 0.5f * (x0r + x1r) + 0.5f * x0i - 0.5f * x1i;
            ui[k1] = 0.5f * (x0i + x1i) - 0.5f * x0r + 0.5f * x1r;
        } else {                                       // CNOT
            ur[k0] = x1r; ui[k0] = x1i;
            ur[k1] = x0r; ui[k1] = x0i;
        }
    }
}

template<int I>
__device__ __forceinline__ void run_enc(float (&ur)[16], float (&ui)[16],
                                        const float* ch, const float* sh)
{
    if constexpr (I < 8) {
        constexpr int op = kOps.enc[I];
        gate_ct<(op >> 4) & 7, (op >> 2) & 3, op & 3>(ur, ui, ch[I], sh[I]);
        run_enc<I + 1>(ur, ui, ch, sh);
    }
}

template<int I>
__device__ __forceinline__ void run_qfc(float (&ur)[16], float (&ui)[16],
                                        const float* ch, const float* sh)
{
    if constexpr (I < 50) {
        constexpr int op = kOps.qfc[I];
        gate_ct<(op >> 4) & 7, (op >> 2) & 3, op & 3>(ur, ui, ch[I], sh[I]);
        run_qfc<I + 1>(ur, ui, ch, sh);
    }
}

// ---------------------------------------------------------------------------
// Kernel 2: fully register-resident quantum sim. Thread = one patch.
// qfeat row-major (coalesced float4 writes — transposed layout regressed in R8).
// ---------------------------------------------------------------------------
__global__ __launch_bounds__(256) void quantum_kernel(
    const float* __restrict__ pm, const float* __restrict__ encp,
    const float* __restrict__ qfcr, const float* __restrict__ qfcp,
    float* __restrict__ qfeat, float* __restrict__ qraw,
    float* __restrict__ stats, int Bv)
{
    __shared__ float chs[62], shs[62];
    __shared__ float rstat[128];

    const int tid = threadIdx.x;
    if (tid < 62) {
        float t = (tid < 8) ? encp[tid] : (tid < 58) ? qfcr[tid - 8] : qfcp[tid - 58];
        chs[tid] = cosf(0.5f * t);
        shs[tid] = sinf(0.5f * t);
    }
    __syncthreads();

    const int gid = blockIdx.x * 256 + tid;
    const int b = gid >> 4, p = gid & 15;
    float qq[4] = {0.f, 0.f, 0.f, 0.f};
    bool last = false;

    if (b < Bv) {
        const int pr = p >> 2, pc = p & 3;
        const float* pmb = pm + (size_t)b * 64;
        float d0 = pmb[(2 * pr) * 8 + 2 * pc];
        float d1 = pmb[(2 * pr) * 8 + 2 * pc + 1];
        float d2 = pmb[(2 * pr + 1) * 8 + 2 * pc];
        float d3 = pmb[(2 * pr + 1) * 8 + 2 * pc + 1];
        float f0c = cosf(0.5f * d0), f0s = sinf(0.5f * d0);
        float f1c = cosf(0.5f * d1), f1s = sinf(0.5f * d1);
        float f2c = cosf(0.5f * d2), f2s = sinf(0.5f * d2);
        float f3c = cosf(0.5f * d3), f3s = sinf(0.5f * d3);

        float ur[16], ui[16];
#pragma unroll
        for (int k = 0; k < 16; ++k) {
            float v = ((k & 8) ? f0s : f0c);
            v *= ((k & 4) ? f1s : f1c);
            v *= ((k & 2) ? f2s : f2c);
            v *= ((k & 1) ? f3s : f3c);
            ur[k] = v;
            ui[k] = 0.f;
        }
        run_enc<0>(ur, ui, chs, shs);

        float qv[4] = {0.f, 0.f, 0.f, 0.f};
#pragma unroll
        for (int k = 0; k < 16; ++k) {
            float pk = ur[k] * ur[k] + ui[k] * ui[k];
            qv[0] += (k & 8) ? -pk : pk;
            qv[1] += (k & 4) ? -pk : pk;
            qv[2] += (k & 2) ? -pk : pk;
            qv[3] += (k & 1) ? -pk : pk;
        }
        *(float4*)(qfeat + (size_t)b * 64 + p * 4) = make_float4(qv[0], qv[1], qv[2], qv[3]);

        if (p == 15) {
            last = true;
            run_qfc<0>(ur, ui, chs + 8, shs + 8);
            gate_ct<0, 0, 0>(ur, ui, chs[58], shs[58]);  // RX wire0
            gate_ct<1, 1, 0>(ur, ui, chs[59], shs[59]);  // RY wire1
            gate_ct<2, 3, 0>(ur, ui, chs[60], shs[60]);  // RZ wire3
            gate_ct<3, 0, 2>(ur, ui, chs[61], shs[61]);  // CRX ctrl0 tgt2
            gate_ct<4, 3, 0>(ur, ui, 0.f, 0.f);          // H wire3
            gate_ct<5, 2, 0>(ur, ui, 0.f, 0.f);          // SX wire2
            gate_ct<6, 3, 0>(ur, ui, 0.f, 0.f);          // CNOT ctrl3 tgt0
#pragma unroll
            for (int k = 0; k < 16; ++k) {
                float pk = ur[k] * ur[k] + ui[k] * ui[k];
                qq[0] += (k & 8) ? -pk : pk;
                qq[1] += (k & 4) ? -pk : pk;
                qq[2] += (k & 2) ? -pk : pk;
                qq[3] += (k & 1) ? -pk : pk;
            }
            *(float4*)(qraw + (size_t)b * 4) = make_float4(qq[0], qq[1], qq[2], qq[3]);
        }
    }

    for (int k = tid; k < 128; k += 256) rstat[k] = 0.f;
    __syncthreads();
    const int m = tid >> 4;
    if (last) {
#pragma unroll
        for (int w = 0; w < 4; ++w) {
            rstat[w * 16 + m] = qq[w];
            rstat[64 + w * 16 + m] = qq[w] * qq[w];
        }
    }
    __syncthreads();
    if (tid < 8) {
        float s = 0.f;
#pragma unroll
        for (int k = 0; k < 16; ++k) s += rstat[tid * 16 + k];
        atomicAdd(&stats[tid], s);
    }
}

// ---------------------------------------------------------------------------
// Kernel 3: BN apply + FC(68->10) + log_softmax (thread = one sample)
// ---------------------------------------------------------------------------
__global__ __launch_bounds__(256) void head_kernel(
    const float* __restrict__ qfeat, const float* __restrict__ qraw,
    const float* __restrict__ stats, const float* __restrict__ gam,
    const float* __restrict__ bet, const float* __restrict__ fcw,
    const float* __restrict__ fcb, float* __restrict__ out, int Bv)
{
    __shared__ float Wf[680];
    __shared__ float bf[10], st[8], ga[4], be[4];
    const int tid = threadIdx.x;
    for (int k = tid; k < 680; k += 256) Wf[k] = fcw[k];
    if (tid < 10) bf[tid] = fcb[tid];
    if (tid < 8) st[tid] = stats[tid];
    if (tid < 4) { ga[tid] = gam[tid]; be[tid] = bet[tid]; }
    __syncthreads();

    const int b = blockIdx.x * 256 + tid;
    if (b >= Bv) return;

    const float invB = 1.f / (float)Bv;

    float logit[10];
#pragma unroll
    for (int k = 0; k < 10; ++k) logit[k] = bf[k];

    const float* qf = qfeat + (size_t)b * 64;
    for (int j = 0; j < 64; ++j) {
        float v = qf[j];
#pragma unroll
        for (int k = 0; k < 10; ++k) logit[k] += v * Wf[k * 68 + j];
    }
    float4 qr = *(const float4*)(qraw + (size_t)b * 4);
    float qn[4] = {qr.x, qr.y, qr.z, qr.w};
#pragma unroll
    for (int w = 0; w < 4; ++w) {
        float mu = st[w] * invB;
        float var = st[4 + w] * invB - mu * mu;
        float v = (qn[w] - mu) / sqrtf(var + 1e-5f) * ga[w] + be[w];
#pragma unroll
        for (int k = 0; k < 10; ++k) logit[k] += v * Wf[k * 68 + 64 + w];
    }

    float m = logit[0];
#pragma unroll
    for (int k = 1; k < 10; ++k) m = fmaxf(m, logit[k]);
    float sum = 0.f;
#pragma unroll
    for (int k = 0; k < 10; ++k) sum += expf(logit[k] - m);
    float lse = logf(sum);
#pragma unroll
    for (int k = 0; k < 10; ++k) out[(size_t)b * 10 + k] = logit[k] - m - lse;
}

// ---------------------------------------------------------------------------
extern "C" void kernel_launch(void* const* d_in, const int* in_sizes, int n_in,
                              void* d_out, int out_size, void* d_ws, size_t ws_size,
                              hipStream_t stream)
{
    const float* x    = (const float*)d_in[0];
    const float* w1   = (const float*)d_in[1];
    const float* b1   = (const float*)d_in[2];
    const float* w2   = (const float*)d_in[3];
    const float* b2   = (const float*)d_in[4];
    const float* encp = (const float*)d_in[5];
    const float* qfcr = (const float*)d_in[6];
    const float* qfcp = (const float*)d_in[7];
    const float* gam  = (const float*)d_in[8];
    const float* bet  = (const float*)d_in[9];
    const float* fcw  = (const float*)d_in[10];
    const float* fcb  = (const float*)d_in[11];
    float* out = (float*)d_out;

    const int Bv = in_sizes[0] / 1024;  // 4096

    float* pm    = (float*)d_ws;                 // Bv*64
    float* qfeat = pm + (size_t)Bv * 64;         // Bv*64
    float* qraw  = qfeat + (size_t)Bv * 64;      // Bv*4
    float* stats = qraw + (size_t)Bv * 4;        // 8

    cnn_kernel<<<Bv, 256, 0, stream>>>(x, w1, b1, w2, b2, pm, stats);
    quantum_kernel<<<(Bv * 16 + 255) / 256, 256, 0, stream>>>(
        pm, encp, qfcr, qfcp, qfeat, qraw, stats, Bv);
    head_kernel<<<(Bv + 255) / 256, 256, 0, stream>>>(qfeat, qraw, stats, gam, bet,
                                                      fcw, fcb, out, Bv);
}